// Round 8
// baseline (108.322 us; speedup 1.0000x reference)
//
#include <hip/hip_runtime.h>
#include <hip/hip_cooperative_groups.h>
#include <math.h>

namespace cg = cooperative_groups;

#define BB 256
#define NN 1000
#define DD 128
#define HH 8
#define QQ 4            // quarters per batch element
#define RQ 250          // rows per quarter
#define NEG -1e9f

__device__ __forceinline__ float bf2f(unsigned int u) {
    return __uint_as_float(u << 16);
}
__device__ __forceinline__ unsigned short f2bf(float f) {
    unsigned int u = __float_as_uint(f);
    u += 0x7FFFu + ((u >> 16) & 1u);          // RNE
    return (unsigned short)(u >> 16);
}
__device__ __forceinline__ bool get_mask(const void* m, int flag, size_t idx) {
    if (flag == 1) return ((const int*)m)[idx] != 0;
    if (flag == 2) return ((const float*)m)[idx] != 0.0f;
    return ((const unsigned char*)m)[idx] != 0;
}

// ===========================================================================
// Cooperative kernel: 1024 blocks = (b, quarter), 256 threads, 4 blocks/CU.
// LDS pool is phase-overlaid (24.5 KB total) to guarantee 4 blocks/CU.
// ===========================================================================
template<int BF16>
__global__ __launch_bounds__(256, 4) void k_coop(
        const float* __restrict__ X, const float* __restrict__ Wnode,
        const float* __restrict__ Wfix, const float* __restrict__ Wstep,
        const float* __restrict__ Wout, const int* __restrict__ prev,
        const int* __restrict__ first, const void* __restrict__ mask,
        int* __restrict__ flag, float* __restrict__ partial,
        float* __restrict__ mqw, float* __restrict__ sqw,
        float* __restrict__ pvp, float* __restrict__ ssum,
        unsigned short* __restrict__ Xb, float* __restrict__ out) {
    cg::grid_group grid = cg::this_grid();
    const int bid = blockIdx.x, tid = threadIdx.x;
    const int b = bid >> 2, q = bid & 3;
    const int n0 = q * RQ;
    const size_t xoff = (size_t)b * NN * DD;

    // --- phase-overlaid LDS pool (16 KB) + cm (8.25 KB) ---
    __shared__ __align__(16) unsigned char pool[16384];
    __shared__ float cm[HH][264];
    // phases 1-2a:
    float4* red4 = (float4*)pool;                 // [8][32]   (phase 1)
    float*  ge   = (float*)(pool + 4096);         // [128]
    float*  sc   = (float*)(pool + 4608);         // [256]
    float*  qv   = (float*)(pool + 5632);         // [128]
    float*  qpart= (float*)(pool + 6144);         // [2][128]  (also phase 3)
    float*  qk   = (float*)(pool + 7168);         // [8][128]
    float*  mloc = (float*)(pool + 11264);        // [8]
    // phase 2 PV:
    float*  xp   = (float*)pool;                  // [4][8][128] = 16 KB
    // phases 3-4:
    float*  wq   = (float*)pool;                  // [4][8]
    float*  Sh   = (float*)(pool + 128);          // [8]
    float*  xa   = (float*)(pool + 512);          // [8][128]
    float*  hd   = (float*)(pool + 4608);         // [128]
    float*  gl   = (float*)(pool + 5120);         // [128]
    float*  gqv  = (float*)(pool + 5632);         // [128]
    float*  lgl  = (float*)(pool + 6144);         // [256] (lives into phase 4)
    float*  redw = (float*)(pool + 7200);         // [4]

    // ================= phase 1: mean partial + bf16 stage ==================
    if (bid == 0 && tid < 64) {
        const unsigned int* mw = (const unsigned int*)mask;
        unsigned int a0 = mw[tid], a1 = mw[tid + 64], a2 = mw[tid + 128], a3 = mw[tid + 192];
        int ii = (a0 <= 1u) && (a1 <= 1u) && (a2 <= 1u) && (a3 <= 1u);
        int ff = (a0 == 0u || a0 == 0x3F800000u) && (a1 == 0u || a1 == 0x3F800000u) &&
                 (a2 == 0u || a2 == 0x3F800000u) && (a3 == 0u || a3 == 0x3F800000u);
        int ai = __all(ii), af = __all(ff);
        if (tid == 0) *flag = ai ? 1 : (af ? 2 : 0);
    }
    {
        int c = tid & 31, s = tid >> 5;
        const float4* Xr = (const float4*)(X + xoff);
        float4 acc = make_float4(0.f, 0.f, 0.f, 0.f);
        for (int nl = s; nl < RQ; nl += 8) {
            int n = n0 + nl;
            float4 v = Xr[n * 32 + c];
            acc.x += v.x; acc.y += v.y; acc.z += v.z; acc.w += v.w;
            if (BF16) {
                uint2 p;
                p.x = (unsigned)f2bf(v.x) | ((unsigned)f2bf(v.y) << 16);
                p.y = (unsigned)f2bf(v.z) | ((unsigned)f2bf(v.w) << 16);
                ((uint2*)Xb)[((size_t)b * NN + n) * 32 + c] = p;
            }
        }
        red4[s * 32 + c] = acc;
        __syncthreads();
        for (int st = 4; st >= 1; st >>= 1) {
            if (s < st) {
                float4 o = red4[(s + st) * 32 + c];
                float4 r = red4[s * 32 + c];
                r.x += o.x; r.y += o.y; r.z += o.z; r.w += o.w;
                red4[s * 32 + c] = r;
            }
            __syncthreads();
        }
        if (s == 0) {
            float4 r = red4[c];
            float* outp = partial + ((size_t)b * QQ + q) * DD + 4 * c;
            outp[0] = r.x; outp[1] = r.y; outp[2] = r.z; outp[3] = r.w;
        }
    }
    grid.sync();

    // ================= phase 2: qk -> compat -> softmax -> PV ==============
    const int f = *flag;
    if (tid < DD) {
        float g = 0.f;
        #pragma unroll
        for (int qq = 0; qq < QQ; ++qq) g += partial[((size_t)b * QQ + qq) * DD + tid];
        ge[tid] = g * (1.0f / NN);
    }
    {
        int src = (tid < DD) ? first[b] : prev[b];
        sc[tid] = X[xoff + (size_t)src * DD + (tid & 127)];
    }
    __syncthreads();
    {   // query vector (split-k over 2 halves)
        int p = tid >> 7, d = tid & 127;
        float a = 0.f;
        #pragma unroll 4
        for (int k = p * 64; k < p * 64 + 64; ++k)     a += ge[k] * Wfix[(size_t)k * DD + d];
        #pragma unroll 4
        for (int k = p * 128; k < p * 128 + 128; ++k)  a += sc[k] * Wstep[(size_t)k * DD + d];
        qpart[p * DD + d] = a;
    }
    __syncthreads();
    if (tid < DD) qv[tid] = qpart[tid] + qpart[DD + tid];
    __syncthreads();
    {   // qk[h][d]
        int hg = tid >> 7, d = tid & 127;
        const float* wrow = Wnode + (size_t)d * 384;
        #pragma unroll
        for (int h = hg * 4; h < hg * 4 + 4; ++h) {
            const float4* wr = (const float4*)(wrow + h * 16);
            float a = 0.f;
            #pragma unroll
            for (int j4 = 0; j4 < 4; ++j4) {
                float4 w = wr[j4];
                a += w.x * qv[h * 16 + 4 * j4]     + w.y * qv[h * 16 + 4 * j4 + 1]
                   + w.z * qv[h * 16 + 4 * j4 + 2] + w.w * qv[h * 16 + 4 * j4 + 3];
            }
            qk[h * DD + d] = 0.25f * a;           // 1/sqrt(16)
        }
    }
    __syncthreads();
    {   // compat, 8 lanes per row
        int g = tid & 7, r = tid >> 3;
        for (int it = 0; it < 8; ++it) {
            int nl = it * 32 + r;
            if (nl < RQ) {
                int n = n0 + nl;
                float acc[HH] = {0.f, 0.f, 0.f, 0.f, 0.f, 0.f, 0.f, 0.f};
                if (BF16) {
                    const uint4* xr = (const uint4*)(Xb + ((size_t)b * NN + n) * DD);
                    uint4 c0 = xr[g], c1 = xr[g + 8];
                    unsigned int wsv[8] = {c0.x, c0.y, c0.z, c0.w, c1.x, c1.y, c1.z, c1.w};
                    #pragma unroll
                    for (int i = 0; i < 8; ++i) {
                        int col = (i < 4) ? (8 * g + 2 * i) : (64 + 8 * g + 2 * (i - 4));
                        float lo = bf2f(wsv[i] & 0xffffu), hi = bf2f(wsv[i] >> 16);
                        #pragma unroll
                        for (int h = 0; h < HH; ++h)
                            acc[h] += lo * qk[h * DD + col] + hi * qk[h * DD + col + 1];
                    }
                } else {
                    const float4* xr = (const float4*)(X + xoff + (size_t)n * DD);
                    #pragma unroll
                    for (int i = 0; i < 4; ++i) {
                        float4 v = xr[g + 8 * i];
                        int col = 4 * (g + 8 * i);
                        #pragma unroll
                        for (int h = 0; h < HH; ++h)
                            acc[h] += v.x * qk[h * DD + col]     + v.y * qk[h * DD + col + 1]
                                    + v.z * qk[h * DD + col + 2] + v.w * qk[h * DD + col + 3];
                    }
                }
                #pragma unroll
                for (int h = 0; h < HH; ++h) {
                    acc[h] += __shfl_xor(acc[h], 1, 8);
                    acc[h] += __shfl_xor(acc[h], 2, 8);
                    acc[h] += __shfl_xor(acc[h], 4, 8);
                }
                float val = acc[0];
                #pragma unroll
                for (int h = 1; h < HH; ++h) val = (g == h) ? acc[h] : val;
                bool mk = get_mask(mask, f, (size_t)b * NN + n);
                cm[g][nl] = mk ? NEG : val;
            }
        }
    }
    __syncthreads();
    {   // local max per head (32 lanes per head)
        int h = tid >> 5, l = tid & 31;
        float mx = -INFINITY;
        for (int nl = l; nl < RQ; nl += 32) mx = fmaxf(mx, cm[h][nl]);
        #pragma unroll
        for (int off = 16; off >= 1; off >>= 1) mx = fmaxf(mx, __shfl_xor(mx, off, 32));
        if (l == 0) mloc[h] = mx;
    }
    __syncthreads();
    {   // exp + local sum
        int h = tid >> 5, l = tid & 31;
        float m_h = mloc[h];
        float sm = 0.f;
        for (int nl = l; nl < RQ; nl += 32) {
            float p = __expf(cm[h][nl] - m_h);
            cm[h][nl] = p;
            sm += p;
        }
        #pragma unroll
        for (int off = 16; off >= 1; off >>= 1) sm += __shfl_xor(sm, off, 32);
        if (l == 0) {
            sqw[((size_t)b * QQ + q) * HH + h] = sm;
            mqw[((size_t)b * QQ + q) * HH + h] = m_h;
        }
    }
    __syncthreads();
    {   // partial PV, paired cols: 4 stripes x 64 col-pairs
        int s4 = tid >> 6, dp = tid & 63;
        float a0[HH] = {0.f, 0.f, 0.f, 0.f, 0.f, 0.f, 0.f, 0.f};
        float a1[HH] = {0.f, 0.f, 0.f, 0.f, 0.f, 0.f, 0.f, 0.f};
        for (int nl = s4; nl < RQ; nl += 4) {
            float x0, x1;
            if (BF16) {
                unsigned int u = *(const unsigned int*)
                    (Xb + ((size_t)b * NN + n0 + nl) * DD + 2 * dp);
                x0 = bf2f(u & 0xffffu); x1 = bf2f(u >> 16);
            } else {
                float2 v = *(const float2*)(X + xoff + (size_t)(n0 + nl) * DD + 2 * dp);
                x0 = v.x; x1 = v.y;
            }
            #pragma unroll
            for (int h = 0; h < HH; ++h) {
                float p = cm[h][nl];
                a0[h] += p * x0; a1[h] += p * x1;
            }
        }
        #pragma unroll
        for (int h = 0; h < HH; ++h) {
            xp[((size_t)s4 * HH + h) * DD + 2 * dp]     = a0[h];
            xp[((size_t)s4 * HH + h) * DD + 2 * dp + 1] = a1[h];
        }
        __syncthreads();
        if (s4 == 0) {
            #pragma unroll
            for (int h = 0; h < HH; ++h) {
                float t0 = 0.f, t1 = 0.f;
                #pragma unroll
                for (int ss = 0; ss < 4; ++ss) {
                    t0 += xp[((size_t)ss * HH + h) * DD + 2 * dp];
                    t1 += xp[((size_t)ss * HH + h) * DD + 2 * dp + 1];
                }
                pvp[(((size_t)b * QQ + q) * HH + h) * DD + 2 * dp]     = t0;
                pvp[(((size_t)b * QQ + q) * HH + h) * DD + 2 * dp + 1] = t1;
            }
        }
    }
    grid.sync();

    // ================= phase 3: combine -> gq -> logits ====================
    if (tid < HH) {
        float m = mqw[((size_t)b * QQ) * HH + tid];
        #pragma unroll
        for (int qq = 1; qq < QQ; ++qq)
            m = fmaxf(m, mqw[((size_t)b * QQ + qq) * HH + tid]);
        float S = 0.f;
        #pragma unroll
        for (int qq = 0; qq < QQ; ++qq) {
            float wgt = __expf(mqw[((size_t)b * QQ + qq) * HH + tid] - m);
            wq[qq * HH + tid] = wgt;
            S += sqw[((size_t)b * QQ + qq) * HH + tid] * wgt;
        }
        Sh[tid] = 1.0f / S;
    }
    __syncthreads();
    for (int idx = tid; idx < HH * DD; idx += 256) {
        int h = idx >> 7, d = idx & 127;
        float a = 0.f;
        #pragma unroll
        for (int qq = 0; qq < QQ; ++qq)
            a += pvp[(((size_t)b * QQ + qq) * HH + h) * DD + d] * wq[qq * HH + h];
        xa[h * DD + d] = a * Sh[h];
    }
    __syncthreads();
    {   // heads -> glimpse -> gq (split-k over 2 halves)
        int p = tid >> 7, t = tid & 127;
        {
            int h = t >> 4;
            float a = 0.f;
            #pragma unroll 4
            for (int d = p * 64; d < p * 64 + 64; ++d)
                a += xa[h * DD + d] * Wnode[(size_t)d * 384 + 128 + t];
            qpart[p * DD + t] = a;
        }
        __syncthreads();
        if (tid < DD) hd[tid] = qpart[tid] + qpart[DD + tid];
        __syncthreads();
        {
            float a = 0.f;
            #pragma unroll 4
            for (int k = p * 64; k < p * 64 + 64; ++k) a += hd[k] * Wout[(size_t)k * DD + t];
            qpart[p * DD + t] = a;
        }
        __syncthreads();
        if (tid < DD) gl[tid] = qpart[tid] + qpart[DD + tid];
        __syncthreads();
        {
            const float4* wr = (const float4*)(Wnode + (size_t)t * 384 + 256 + p * 64);
            float a = 0.f;
            #pragma unroll
            for (int j4 = 0; j4 < 16; ++j4) {
                float4 w = wr[j4];
                int k = p * 64 + 4 * j4;
                a += w.x * gl[k] + w.y * gl[k + 1] + w.z * gl[k + 2] + w.w * gl[k + 3];
            }
            qpart[p * DD + t] = a;
        }
        __syncthreads();
        if (tid < DD) gqv[tid] = (qpart[tid] + qpart[DD + tid]) * 0.08838834764831845f;
    }
    __syncthreads();
    {   // logits for own quarter, exp-partials at fixed base 10
        int g = tid & 7, r = tid >> 3;
        float esum = 0.f;
        for (int it = 0; it < 8; ++it) {
            int nl = it * 32 + r;
            if (nl < RQ) {
                int n = n0 + nl;
                float a = 0.f;
                if (BF16) {
                    const uint4* xr = (const uint4*)(Xb + ((size_t)b * NN + n) * DD);
                    uint4 c0 = xr[g], c1 = xr[g + 8];
                    unsigned int wsv[8] = {c0.x, c0.y, c0.z, c0.w, c1.x, c1.y, c1.z, c1.w};
                    #pragma unroll
                    for (int i = 0; i < 8; ++i) {
                        int col = (i < 4) ? (8 * g + 2 * i) : (64 + 8 * g + 2 * (i - 4));
                        a += bf2f(wsv[i] & 0xffffu) * gqv[col] + bf2f(wsv[i] >> 16) * gqv[col + 1];
                    }
                } else {
                    const float4* xr = (const float4*)(X + xoff + (size_t)n * DD);
                    #pragma unroll
                    for (int i = 0; i < 4; ++i) {
                        float4 v = xr[g + 8 * i];
                        int col = 4 * (g + 8 * i);
                        a += v.x * gqv[col] + v.y * gqv[col + 1]
                           + v.z * gqv[col + 2] + v.w * gqv[col + 3];
                    }
                }
                a += __shfl_xor(a, 1, 8);
                a += __shfl_xor(a, 2, 8);
                a += __shfl_xor(a, 4, 8);
                if (g == 0) {
                    float l = 10.0f * tanhf(a);
                    if (get_mask(mask, f, (size_t)b * NN + n)) l = NEG;
                    lgl[nl] = l;
                    esum += __expf(l - 10.0f);      // logits <= 10 always
                }
            }
        }
        #pragma unroll
        for (int off = 32; off >= 1; off >>= 1) esum += __shfl_xor(esum, off, 64);
        if ((tid & 63) == 0) redw[tid >> 6] = esum;
        __syncthreads();
        if (tid == 0) ssum[(size_t)b * QQ + q] = redw[0] + redw[1] + redw[2] + redw[3];
    }
    grid.sync();

    // ================= phase 4: lse + store ================================
    {
        float s = ssum[(size_t)b * QQ] + ssum[(size_t)b * QQ + 1]
                + ssum[(size_t)b * QQ + 2] + ssum[(size_t)b * QQ + 3];
        float lse = 10.0f + logf(s);
        for (int nl = tid; nl < RQ; nl += 256)
            out[(size_t)b * NN + n0 + nl] = lgl[nl] - lse;
    }
}

// ===========================================================================
// Fallback: proven round-3 mega-kernel (one block per b, 1024 threads).
// ===========================================================================
template<int BF16>
__global__ __launch_bounds__(1024) void k_fused(
        const float* __restrict__ X, const float* __restrict__ Wnode,
        const float* __restrict__ Wfix, const float* __restrict__ Wstep,
        const float* __restrict__ Wout, const int* __restrict__ prev,
        const int* __restrict__ first, const void* __restrict__ mask,
        unsigned short* __restrict__ Xb, float* __restrict__ out) {
    int b = blockIdx.x, tid = threadIdx.x;

    __shared__ __align__(16) float cm[HH * 1024];
    __shared__ __align__(16) float qkl[HH * DD];
    __shared__ __align__(16) float qpart[8 * DD];
    __shared__ float xa[HH * DD];
    __shared__ float ge[DD], q[DD], sc[2 * DD], hd[DD], gl[DD], gqv[DD];
    __shared__ float red[16], invh[8];
    __shared__ int s_flag;

    const size_t xoff = (size_t)b * NN * DD;

    if (tid < 64) {
        const unsigned int* mw = (const unsigned int*)mask;
        unsigned int a0 = mw[tid], a1 = mw[tid + 64], a2 = mw[tid + 128], a3 = mw[tid + 192];
        int ii = (a0 <= 1u) && (a1 <= 1u) && (a2 <= 1u) && (a3 <= 1u);
        int ff = (a0 == 0u || a0 == 0x3F800000u) && (a1 == 0u || a1 == 0x3F800000u) &&
                 (a2 == 0u || a2 == 0x3F800000u) && (a3 == 0u || a3 == 0x3F800000u);
        int ai = __all(ii), af = __all(ff);
        if (tid == 0) s_flag = ai ? 1 : (af ? 2 : 0);
    }
    if (tid >= 256 && tid < 512) {
        int t = tid - 256;
        int src = (t < DD) ? first[b] : prev[b];
        sc[t] = X[xoff + (size_t)src * DD + (t & 127)];
    }

    {
        float4* red4 = (float4*)cm;
        int c = tid & 31, s = tid >> 5;
        const float4* Xr = (const float4*)(X + xoff);
        float4 acc = make_float4(0.f, 0.f, 0.f, 0.f);
        for (int n = s; n < NN; n += 32) {
            float4 v = Xr[n * 32 + c];
            acc.x += v.x; acc.y += v.y; acc.z += v.z; acc.w += v.w;
            if (BF16) {
                uint2 p;
                p.x = (unsigned)f2bf(v.x) | ((unsigned)f2bf(v.y) << 16);
                p.y = (unsigned)f2bf(v.z) | ((unsigned)f2bf(v.w) << 16);
                ((uint2*)Xb)[(size_t)b * NN * 32 + n * 32 + c] = p;
            }
        }
        red4[s * 32 + c] = acc;
        __syncthreads();
        for (int st = 16; st >= 1; st >>= 1) {
            if (s < st) {
                float4 o = red4[(s + st) * 32 + c];
                float4 r = red4[s * 32 + c];
                r.x += o.x; r.y += o.y; r.z += o.z; r.w += o.w;
                red4[s * 32 + c] = r;
            }
            __syncthreads();
        }
        if (s == 0) {
            float4 r = red4[c];
            ge[4 * c]     = r.x * (1.0f / NN);
            ge[4 * c + 1] = r.y * (1.0f / NN);
            ge[4 * c + 2] = r.z * (1.0f / NN);
            ge[4 * c + 3] = r.w * (1.0f / NN);
        }
        __syncthreads();
    }
    const int flag = s_flag;

    {
        int p = tid >> 7, d = tid & 127;
        float a = 0.f;
        #pragma unroll 4
        for (int k = p * 16; k < p * 16 + 16; ++k) a += ge[k] * Wfix[k * DD + d];
        #pragma unroll 4
        for (int k = p * 32; k < p * 32 + 32; ++k) a += sc[k] * Wstep[k * DD + d];
        qpart[p * DD + d] = a;
        __syncthreads();
        if (tid < DD) {
            float s = 0.f;
            #pragma unroll
            for (int pp = 0; pp < 8; ++pp) s += qpart[pp * DD + tid];
            q[tid] = s;
        }
        __syncthreads();
        int d2 = tid >> 3, h = tid & 7;
        const float4* wr = (const float4*)(Wnode + (size_t)d2 * 384 + h * 16);
        float a2 = 0.f;
        #pragma unroll
        for (int j4 = 0; j4 < 4; ++j4) {
            float4 w = wr[j4];
            a2 += w.x * q[h * 16 + 4 * j4]     + w.y * q[h * 16 + 4 * j4 + 1]
                + w.z * q[h * 16 + 4 * j4 + 2] + w.w * q[h * 16 + 4 * j4 + 3];
        }
        qkl[h * DD + d2] = 0.25f * a2;
        __syncthreads();
    }

    {
        int g = tid & 7;
        for (int it = 0; it < 8; ++it) {
            int n = it * 128 + (tid >> 3);
            if (n < NN) {
                float acc[HH] = {0.f, 0.f, 0.f, 0.f, 0.f, 0.f, 0.f, 0.f};
                if (BF16) {
                    const uint4* xr = (const uint4*)(Xb + xoff + (size_t)n * DD);
                    uint4 c0 = xr[g], c1 = xr[g + 8];
                    unsigned int wsv[8] = {c0.x, c0.y, c0.z, c0.w, c1.x, c1.y, c1.z, c1.w};
                    #pragma unroll
                    for (int i = 0; i < 8; ++i) {
                        int col = (i < 4) ? (8 * g + 2 * i) : (64 + 8 * g + 2 * (i - 4));
                        float lo = bf2f(wsv[i] & 0xffffu), hi = bf2f(wsv[i] >> 16);
                        #pragma unroll
                        for (int h = 0; h < HH; ++h)
                            acc[h] += lo * qkl[h * DD + col] + hi * qkl[h * DD + col + 1];
                    }
                } else {
                    const float4* xr = (const float4*)(X + xoff + (size_t)n * DD);
                    #pragma unroll
                    for (int i = 0; i < 4; ++i) {
                        float4 v = xr[g + 8 * i];
                        int col = 4 * (g + 8 * i);
                        #pragma unroll
                        for (int h = 0; h < HH; ++h)
                            acc[h] += v.x * qkl[h * DD + col]     + v.y * qkl[h * DD + col + 1]
                                    + v.z * qkl[h * DD + col + 2] + v.w * qkl[h * DD + col + 3];
                    }
                }
                #pragma unroll
                for (int h = 0; h < HH; ++h) {
                    acc[h] += __shfl_xor(acc[h], 1, 8);
                    acc[h] += __shfl_xor(acc[h], 2, 8);
                    acc[h] += __shfl_xor(acc[h], 4, 8);
                }
                float val = acc[0];
                #pragma unroll
                for (int h = 1; h < HH; ++h) val = (g == h) ? acc[h] : val;
                bool mk = get_mask(mask, flag, (size_t)b * NN + n);
                cm[g * 1024 + n] = mk ? NEG : val;
            }
        }
        __syncthreads();
    }

    {
        int h = tid >> 7, lane = tid & 127;
        float mx = -INFINITY;
        for (int n = lane; n < NN; n += 128) mx = fmaxf(mx, cm[h * 1024 + n]);
        #pragma unroll
        for (int off = 32; off >= 1; off >>= 1) mx = fmaxf(mx, __shfl_xor(mx, off, 64));
        if ((tid & 63) == 0) red[tid >> 6] = mx;
        __syncthreads();
        float m_h = fmaxf(red[2 * h], red[2 * h + 1]);
        float sm = 0.f;
        for (int n = lane; n < NN; n += 128) {
            float p = __expf(cm[h * 1024 + n] - m_h);
            cm[h * 1024 + n] = p;
            sm += p;
        }
        #pragma unroll
        for (int off = 32; off >= 1; off >>= 1) sm += __shfl_xor(sm, off, 64);
        __syncthreads();
        if ((tid & 63) == 0) red[tid >> 6] = sm;
        __syncthreads();
        if (tid < HH) invh[tid] = 1.0f / (red[2 * tid] + red[2 * tid + 1]);
        __syncthreads();
    }

    {
        int s = tid >> 7, d = tid & 127;
        float acc[HH] = {0.f, 0.f, 0.f, 0.f, 0.f, 0.f, 0.f, 0.f};
        for (int n = s; n < NN; n += 8) {
            float x = BF16 ? bf2f((unsigned int)Xb[xoff + (size_t)n * DD + d])
                           : X[xoff + (size_t)n * DD + d];
            #pragma unroll
            for (int h = 0; h < HH; ++h) acc[h] += cm[h * 1024 + n] * x;
        }
        __syncthreads();
        float* xp = cm;
        #pragma unroll
        for (int h = 0; h < HH; ++h) xp[(s * HH + h) * DD + d] = acc[h];
        __syncthreads();
        if (s == 0) {
            #pragma unroll
            for (int h = 0; h < HH; ++h) {
                float t = 0.f;
                #pragma unroll
                for (int ss = 0; ss < 8; ++ss) t += xp[(ss * HH + h) * DD + d];
                xa[h * DD + d] = t * invh[h];
            }
        }
        __syncthreads();
    }

    {
        int p = tid >> 7, t = tid & 127;
        int h = t >> 4;
        float a = 0.f;
        #pragma unroll 4
        for (int d = p * 16; d < p * 16 + 16; ++d)
            a += xa[h * DD + d] * Wnode[(size_t)d * 384 + 128 + t];
        qpart[p * DD + t] = a;
        __syncthreads();
        if (tid < DD) {
            float s = 0.f;
            #pragma unroll
            for (int pp = 0; pp < 8; ++pp) s += qpart[pp * DD + tid];
            hd[tid] = s;
        }
        __syncthreads();
        a = 0.f;
        #pragma unroll 4
        for (int k = p * 16; k < p * 16 + 16; ++k) a += hd[k] * Wout[(size_t)k * DD + t];
        qpart[p * DD + t] = a;
        __syncthreads();
        if (tid < DD) {
            float s = 0.f;
            #pragma unroll
            for (int pp = 0; pp < 8; ++pp) s += qpart[pp * DD + tid];
            gl[tid] = s;
        }
        __syncthreads();
        const float4* wr = (const float4*)(Wnode + (size_t)t * 384 + 256 + p * 16);
        a = 0.f;
        #pragma unroll
        for (int j4 = 0; j4 < 4; ++j4) {
            float4 w = wr[j4];
            int k = p * 16 + 4 * j4;
            a += w.x * gl[k] + w.y * gl[k + 1] + w.z * gl[k + 2] + w.w * gl[k + 3];
        }
        qpart[p * DD + t] = a;
        __syncthreads();
        if (tid < DD) {
            float s = 0.f;
            #pragma unroll
            for (int pp = 0; pp < 8; ++pp) s += qpart[pp * DD + tid];
            gqv[tid] = s * 0.08838834764831845f;
        }
        __syncthreads();
    }

    {
        float* lg = qkl;
        int g = tid & 7;
        for (int it = 0; it < 8; ++it) {
            int n = it * 128 + (tid >> 3);
            if (n < NN) {
                float a = 0.f;
                if (BF16) {
                    const uint4* xr = (const uint4*)(Xb + xoff + (size_t)n * DD);
                    uint4 c0 = xr[g], c1 = xr[g + 8];
                    unsigned int wsv[8] = {c0.x, c0.y, c0.z, c0.w, c1.x, c1.y, c1.z, c1.w};
                    #pragma unroll
                    for (int i = 0; i < 8; ++i) {
                        int col = (i < 4) ? (8 * g + 2 * i) : (64 + 8 * g + 2 * (i - 4));
                        a += bf2f(wsv[i] & 0xffffu) * gqv[col] + bf2f(wsv[i] >> 16) * gqv[col + 1];
                    }
                } else {
                    const float4* xr = (const float4*)(X + xoff + (size_t)n * DD);
                    #pragma unroll
                    for (int i = 0; i < 4; ++i) {
                        float4 v = xr[g + 8 * i];
                        int col = 4 * (g + 8 * i);
                        a += v.x * gqv[col] + v.y * gqv[col + 1] + v.z * gqv[col + 2] + v.w * gqv[col + 3];
                    }
                }
                a += __shfl_xor(a, 1, 8);
                a += __shfl_xor(a, 2, 8);
                a += __shfl_xor(a, 4, 8);
                if (g == 0) {
                    float lgt = 10.0f * tanhf(a);
                    lg[n] = get_mask(mask, flag, (size_t)b * NN + n) ? NEG : lgt;
                }
            }
        }
        __syncthreads();
        float v = (tid < NN) ? lg[tid] : -INFINITY;
        float mx = v;
        #pragma unroll
        for (int off = 32; off >= 1; off >>= 1) mx = fmaxf(mx, __shfl_xor(mx, off, 64));
        if ((tid & 63) == 0) red[tid >> 6] = mx;
        __syncthreads();
        float m = red[0];
        #pragma unroll
        for (int w = 1; w < 16; ++w) m = fmaxf(m, red[w]);
        float e = (tid < NN) ? __expf(v - m) : 0.f;
        float sm = e;
        #pragma unroll
        for (int off = 32; off >= 1; off >>= 1) sm += __shfl_xor(sm, off, 64);
        __syncthreads();
        if ((tid & 63) == 0) red[tid >> 6] = sm;
        __syncthreads();
        float s2 = 0.f;
        #pragma unroll
        for (int w = 0; w < 16; ++w) s2 += red[w];
        float lse = m + logf(s2);
        if (tid < NN) out[(size_t)b * NN + tid] = v - lse;
    }
}

// ---------------------------------------------------------------------------
extern "C" void kernel_launch(void* const* d_in, const int* in_sizes, int n_in,
                              void* d_out, int out_size, void* d_ws, size_t ws_size,
                              hipStream_t stream) {
    const float* X     = (const float*)d_in[0];
    const float* Wnode = (const float*)d_in[1];
    const float* Wfix  = (const float*)d_in[2];
    const float* Wstep = (const float*)d_in[3];
    const float* Wout  = (const float*)d_in[4];
    const int*   prev  = (const int*)d_in[5];
    const int*   first = (const int*)d_in[6];
    const void*  mask  = d_in[7];
    float* out = (float*)d_out;

    char* wsb = (char*)d_ws;
    int*   flag    = (int*)wsb;
    float* partial = (float*)(wsb + 256);
    float* mqw     = partial + (size_t)BB * QQ * DD;
    float* sqw     = mqw + (size_t)BB * QQ * HH;
    float* pvp     = sqw + (size_t)BB * QQ * HH;
    float* ssum    = pvp + (size_t)BB * QQ * HH * DD;
    const size_t scratch_end = 256 + sizeof(float) *
        ((size_t)BB * QQ * DD + 2 * (size_t)BB * QQ * HH +
         (size_t)BB * QQ * HH * DD + (size_t)BB * QQ);
    const size_t xb_off = (scratch_end + 255) & ~(size_t)255;
    unsigned short* Xb = (unsigned short*)(wsb + xb_off);
    const size_t coop_need_bf16 = xb_off + (size_t)2 * BB * NN * DD;

    bool launched = false;
    if (ws_size >= scratch_end) {
        const int want_bf16 = (ws_size >= coop_need_bf16) ? 1 : 0;
        const void* kptr = want_bf16 ? (const void*)k_coop<1> : (const void*)k_coop<0>;
        int maxb = 0;
        if (hipOccupancyMaxActiveBlocksPerMultiprocessor(&maxb, kptr, 256, 0) == hipSuccess
            && maxb >= 4) {
            unsigned short* xbp = want_bf16 ? Xb : nullptr;
            void* args[] = {(void*)&X, (void*)&Wnode, (void*)&Wfix, (void*)&Wstep,
                            (void*)&Wout, (void*)&prev, (void*)&first, (void*)&mask,
                            (void*)&flag, (void*)&partial, (void*)&mqw, (void*)&sqw,
                            (void*)&pvp, (void*)&ssum, (void*)&xbp, (void*)&out};
            dim3 g(BB * QQ), blk(256);
            launched = (hipLaunchCooperativeKernel(kptr, g, blk, args, 0, stream)
                        == hipSuccess);
        }
    }
    if (!launched) {
        // proven round-3 mega-kernel fallback
        const size_t mega_need = 256 + (size_t)2 * BB * NN * DD;
        if (ws_size >= mega_need) {
            unsigned short* Xm = (unsigned short*)(wsb + 256);
            k_fused<1><<<BB, 1024, 0, stream>>>(X, Wnode, Wfix, Wstep, Wout,
                                                prev, first, mask, Xm, out);
        } else {
            k_fused<0><<<BB, 1024, 0, stream>>>(X, Wnode, Wfix, Wstep, Wout,
                                                prev, first, mask, nullptr, out);
        }
    }
}

// Round 9
// 108.053 us; speedup vs baseline: 1.0025x; 1.0025x over previous
//
#include <hip/hip_runtime.h>
#include <hip/hip_cooperative_groups.h>
#include <math.h>

namespace cg = cooperative_groups;

#define BB 256
#define NN 1000
#define DD 128
#define HH 8
#define QQ 4            // quarters per batch element
#define RQ 250          // rows per quarter
#define NEG -1e9f

__device__ __forceinline__ float bf2f(unsigned int u) {
    return __uint_as_float(u << 16);
}
__device__ __forceinline__ unsigned short f2bf(float f) {
    unsigned int u = __float_as_uint(f);
    u += 0x7FFFu + ((u >> 16) & 1u);          // RNE
    return (unsigned short)(u >> 16);
}
__device__ __forceinline__ bool get_mask(const void* m, int flag, size_t idx) {
    if (flag == 1) return ((const int*)m)[idx] != 0;
    if (flag == 2) return ((const float*)m)[idx] != 0.0f;
    return ((const unsigned char*)m)[idx] != 0;
}

// ===========================================================================
// Cooperative kernel: 1024 blocks = (b, quarter), 256 threads, 4 blocks/CU.
// LDS pool is phase-overlaid (24.5 KB total) to guarantee 4 blocks/CU.
// ===========================================================================
template<int BF16>
__global__ __launch_bounds__(256, 4) void k_coop(
        const float* __restrict__ X, const float* __restrict__ Wnode,
        const float* __restrict__ Wfix, const float* __restrict__ Wstep,
        const float* __restrict__ Wout, const int* __restrict__ prev,
        const int* __restrict__ first, const void* __restrict__ mask,
        int* __restrict__ flag, float* __restrict__ partial,
        float* __restrict__ mqw, float* __restrict__ sqw,
        float* __restrict__ pvp, float* __restrict__ ssum,
        unsigned short* __restrict__ Xb, float* __restrict__ out) {
    cg::grid_group grid = cg::this_grid();
    const int bid = blockIdx.x, tid = threadIdx.x;
    const int b = bid >> 2, q = bid & 3;
    const int n0 = q * RQ;
    const size_t xoff = (size_t)b * NN * DD;

    // --- phase-overlaid LDS pool (16 KB) + cm (8.25 KB) ---
    __shared__ __align__(16) unsigned char pool[16384];
    __shared__ float cm[HH][264];
    // phases 1-2a:
    float4* red4 = (float4*)pool;                 // [8][32]   (phase 1)
    float*  ge   = (float*)(pool + 4096);         // [128]
    float*  sc   = (float*)(pool + 4608);         // [256]
    float*  qv   = (float*)(pool + 5632);         // [128]
    float*  qpart= (float*)(pool + 6144);         // [2][128]  (also phase 3)
    float*  qk   = (float*)(pool + 7168);         // [8][128]
    float*  mloc = (float*)(pool + 11264);        // [8]
    // phase 2 PV:
    float*  xp   = (float*)pool;                  // [4][8][128] = 16 KB
    // phases 3-4:
    float*  wq   = (float*)pool;                  // [4][8]
    float*  Sh   = (float*)(pool + 128);          // [8]
    float*  xa   = (float*)(pool + 512);          // [8][128]
    float*  hd   = (float*)(pool + 4608);         // [128]
    float*  gl   = (float*)(pool + 5120);         // [128]
    float*  gqv  = (float*)(pool + 5632);         // [128]
    float*  lgl  = (float*)(pool + 6144);         // [256] (lives into phase 4)
    float*  redw = (float*)(pool + 7200);         // [4]

    // ================= phase 1: mean partial + bf16 stage ==================
    if (bid == 0 && tid < 64) {
        const unsigned int* mw = (const unsigned int*)mask;
        unsigned int a0 = mw[tid], a1 = mw[tid + 64], a2 = mw[tid + 128], a3 = mw[tid + 192];
        int ii = (a0 <= 1u) && (a1 <= 1u) && (a2 <= 1u) && (a3 <= 1u);
        int ff = (a0 == 0u || a0 == 0x3F800000u) && (a1 == 0u || a1 == 0x3F800000u) &&
                 (a2 == 0u || a2 == 0x3F800000u) && (a3 == 0u || a3 == 0x3F800000u);
        int ai = __all(ii), af = __all(ff);
        if (tid == 0) *flag = ai ? 1 : (af ? 2 : 0);
    }
    {
        int c = tid & 31, s = tid >> 5;
        const float4* Xr = (const float4*)(X + xoff);
        float4 acc = make_float4(0.f, 0.f, 0.f, 0.f);
        for (int nl = s; nl < RQ; nl += 8) {
            int n = n0 + nl;
            float4 v = Xr[n * 32 + c];
            acc.x += v.x; acc.y += v.y; acc.z += v.z; acc.w += v.w;
            if (BF16) {
                uint2 p;
                p.x = (unsigned)f2bf(v.x) | ((unsigned)f2bf(v.y) << 16);
                p.y = (unsigned)f2bf(v.z) | ((unsigned)f2bf(v.w) << 16);
                ((uint2*)Xb)[((size_t)b * NN + n) * 32 + c] = p;
            }
        }
        red4[s * 32 + c] = acc;
        __syncthreads();
        for (int st = 4; st >= 1; st >>= 1) {
            if (s < st) {
                float4 o = red4[(s + st) * 32 + c];
                float4 r = red4[s * 32 + c];
                r.x += o.x; r.y += o.y; r.z += o.z; r.w += o.w;
                red4[s * 32 + c] = r;
            }
            __syncthreads();
        }
        if (s == 0) {
            float4 r = red4[c];
            float* outp = partial + ((size_t)b * QQ + q) * DD + 4 * c;
            outp[0] = r.x; outp[1] = r.y; outp[2] = r.z; outp[3] = r.w;
        }
    }
    grid.sync();

    // ================= phase 2: qk -> compat -> softmax -> PV ==============
    const int f = *flag;
    if (tid < DD) {
        float g = 0.f;
        #pragma unroll
        for (int qq = 0; qq < QQ; ++qq) g += partial[((size_t)b * QQ + qq) * DD + tid];
        ge[tid] = g * (1.0f / NN);
    }
    {
        int src = (tid < DD) ? first[b] : prev[b];
        sc[tid] = X[xoff + (size_t)src * DD + (tid & 127)];
    }
    __syncthreads();
    {   // query vector (split-k over 2 halves)
        int p = tid >> 7, d = tid & 127;
        float a = 0.f;
        #pragma unroll 4
        for (int k = p * 64; k < p * 64 + 64; ++k)     a += ge[k] * Wfix[(size_t)k * DD + d];
        #pragma unroll 4
        for (int k = p * 128; k < p * 128 + 128; ++k)  a += sc[k] * Wstep[(size_t)k * DD + d];
        qpart[p * DD + d] = a;
    }
    __syncthreads();
    if (tid < DD) qv[tid] = qpart[tid] + qpart[DD + tid];
    __syncthreads();
    {   // qk[h][d]
        int hg = tid >> 7, d = tid & 127;
        const float* wrow = Wnode + (size_t)d * 384;
        #pragma unroll
        for (int h = hg * 4; h < hg * 4 + 4; ++h) {
            const float4* wr = (const float4*)(wrow + h * 16);
            float a = 0.f;
            #pragma unroll
            for (int j4 = 0; j4 < 4; ++j4) {
                float4 w = wr[j4];
                a += w.x * qv[h * 16 + 4 * j4]     + w.y * qv[h * 16 + 4 * j4 + 1]
                   + w.z * qv[h * 16 + 4 * j4 + 2] + w.w * qv[h * 16 + 4 * j4 + 3];
            }
            qk[h * DD + d] = 0.25f * a;           // 1/sqrt(16)
        }
    }
    __syncthreads();
    {   // compat, 8 lanes per row
        int g = tid & 7, r = tid >> 3;
        for (int it = 0; it < 8; ++it) {
            int nl = it * 32 + r;
            if (nl < RQ) {
                int n = n0 + nl;
                float acc[HH] = {0.f, 0.f, 0.f, 0.f, 0.f, 0.f, 0.f, 0.f};
                if (BF16) {
                    const uint4* xr = (const uint4*)(Xb + ((size_t)b * NN + n) * DD);
                    uint4 c0 = xr[g], c1 = xr[g + 8];
                    unsigned int wsv[8] = {c0.x, c0.y, c0.z, c0.w, c1.x, c1.y, c1.z, c1.w};
                    #pragma unroll
                    for (int i = 0; i < 8; ++i) {
                        int col = (i < 4) ? (8 * g + 2 * i) : (64 + 8 * g + 2 * (i - 4));
                        float lo = bf2f(wsv[i] & 0xffffu), hi = bf2f(wsv[i] >> 16);
                        #pragma unroll
                        for (int h = 0; h < HH; ++h)
                            acc[h] += lo * qk[h * DD + col] + hi * qk[h * DD + col + 1];
                    }
                } else {
                    const float4* xr = (const float4*)(X + xoff + (size_t)n * DD);
                    #pragma unroll
                    for (int i = 0; i < 4; ++i) {
                        float4 v = xr[g + 8 * i];
                        int col = 4 * (g + 8 * i);
                        #pragma unroll
                        for (int h = 0; h < HH; ++h)
                            acc[h] += v.x * qk[h * DD + col]     + v.y * qk[h * DD + col + 1]
                                    + v.z * qk[h * DD + col + 2] + v.w * qk[h * DD + col + 3];
                    }
                }
                #pragma unroll
                for (int h = 0; h < HH; ++h) {
                    acc[h] += __shfl_xor(acc[h], 1, 8);
                    acc[h] += __shfl_xor(acc[h], 2, 8);
                    acc[h] += __shfl_xor(acc[h], 4, 8);
                }
                float val = acc[0];
                #pragma unroll
                for (int h = 1; h < HH; ++h) val = (g == h) ? acc[h] : val;
                bool mk = get_mask(mask, f, (size_t)b * NN + n);
                cm[g][nl] = mk ? NEG : val;
            }
        }
    }
    __syncthreads();
    {   // local max per head (32 lanes per head)
        int h = tid >> 5, l = tid & 31;
        float mx = -INFINITY;
        for (int nl = l; nl < RQ; nl += 32) mx = fmaxf(mx, cm[h][nl]);
        #pragma unroll
        for (int off = 16; off >= 1; off >>= 1) mx = fmaxf(mx, __shfl_xor(mx, off, 32));
        if (l == 0) mloc[h] = mx;
    }
    __syncthreads();
    {   // exp + local sum
        int h = tid >> 5, l = tid & 31;
        float m_h = mloc[h];
        float sm = 0.f;
        for (int nl = l; nl < RQ; nl += 32) {
            float p = __expf(cm[h][nl] - m_h);
            cm[h][nl] = p;
            sm += p;
        }
        #pragma unroll
        for (int off = 16; off >= 1; off >>= 1) sm += __shfl_xor(sm, off, 32);
        if (l == 0) {
            sqw[((size_t)b * QQ + q) * HH + h] = sm;
            mqw[((size_t)b * QQ + q) * HH + h] = m_h;
        }
    }
    __syncthreads();
    {   // partial PV, paired cols: 4 stripes x 64 col-pairs
        int s4 = tid >> 6, dp = tid & 63;
        float a0[HH] = {0.f, 0.f, 0.f, 0.f, 0.f, 0.f, 0.f, 0.f};
        float a1[HH] = {0.f, 0.f, 0.f, 0.f, 0.f, 0.f, 0.f, 0.f};
        for (int nl = s4; nl < RQ; nl += 4) {
            float x0, x1;
            if (BF16) {
                unsigned int u = *(const unsigned int*)
                    (Xb + ((size_t)b * NN + n0 + nl) * DD + 2 * dp);
                x0 = bf2f(u & 0xffffu); x1 = bf2f(u >> 16);
            } else {
                float2 v = *(const float2*)(X + xoff + (size_t)(n0 + nl) * DD + 2 * dp);
                x0 = v.x; x1 = v.y;
            }
            #pragma unroll
            for (int h = 0; h < HH; ++h) {
                float p = cm[h][nl];
                a0[h] += p * x0; a1[h] += p * x1;
            }
        }
        #pragma unroll
        for (int h = 0; h < HH; ++h) {
            xp[((size_t)s4 * HH + h) * DD + 2 * dp]     = a0[h];
            xp[((size_t)s4 * HH + h) * DD + 2 * dp + 1] = a1[h];
        }
        __syncthreads();
        if (s4 == 0) {
            #pragma unroll
            for (int h = 0; h < HH; ++h) {
                float t0 = 0.f, t1 = 0.f;
                #pragma unroll
                for (int ss = 0; ss < 4; ++ss) {
                    t0 += xp[((size_t)ss * HH + h) * DD + 2 * dp];
                    t1 += xp[((size_t)ss * HH + h) * DD + 2 * dp + 1];
                }
                pvp[(((size_t)b * QQ + q) * HH + h) * DD + 2 * dp]     = t0;
                pvp[(((size_t)b * QQ + q) * HH + h) * DD + 2 * dp + 1] = t1;
            }
        }
    }
    grid.sync();

    // ================= phase 3: combine -> gq -> logits ====================
    if (tid < HH) {
        float m = mqw[((size_t)b * QQ) * HH + tid];
        #pragma unroll
        for (int qq = 1; qq < QQ; ++qq)
            m = fmaxf(m, mqw[((size_t)b * QQ + qq) * HH + tid]);
        float S = 0.f;
        #pragma unroll
        for (int qq = 0; qq < QQ; ++qq) {
            float wgt = __expf(mqw[((size_t)b * QQ + qq) * HH + tid] - m);
            wq[qq * HH + tid] = wgt;
            S += sqw[((size_t)b * QQ + qq) * HH + tid] * wgt;
        }
        Sh[tid] = 1.0f / S;
    }
    __syncthreads();
    for (int idx = tid; idx < HH * DD; idx += 256) {
        int h = idx >> 7, d = idx & 127;
        float a = 0.f;
        #pragma unroll
        for (int qq = 0; qq < QQ; ++qq)
            a += pvp[(((size_t)b * QQ + qq) * HH + h) * DD + d] * wq[qq * HH + h];
        xa[h * DD + d] = a * Sh[h];
    }
    __syncthreads();
    {   // heads -> glimpse -> gq (split-k over 2 halves)
        int p = tid >> 7, t = tid & 127;
        {
            int h = t >> 4;
            float a = 0.f;
            #pragma unroll 4
            for (int d = p * 64; d < p * 64 + 64; ++d)
                a += xa[h * DD + d] * Wnode[(size_t)d * 384 + 128 + t];
            qpart[p * DD + t] = a;
        }
        __syncthreads();
        if (tid < DD) hd[tid] = qpart[tid] + qpart[DD + tid];
        __syncthreads();
        {
            float a = 0.f;
            #pragma unroll 4
            for (int k = p * 64; k < p * 64 + 64; ++k) a += hd[k] * Wout[(size_t)k * DD + t];
            qpart[p * DD + t] = a;
        }
        __syncthreads();
        if (tid < DD) gl[tid] = qpart[tid] + qpart[DD + tid];
        __syncthreads();
        {
            const float4* wr = (const float4*)(Wnode + (size_t)t * 384 + 256 + p * 64);
            float a = 0.f;
            #pragma unroll
            for (int j4 = 0; j4 < 16; ++j4) {
                float4 w = wr[j4];
                int k = p * 64 + 4 * j4;
                a += w.x * gl[k] + w.y * gl[k + 1] + w.z * gl[k + 2] + w.w * gl[k + 3];
            }
            qpart[p * DD + t] = a;
        }
        __syncthreads();
        if (tid < DD) gqv[tid] = (qpart[tid] + qpart[DD + tid]) * 0.08838834764831845f;
    }
    __syncthreads();
    {   // logits for own quarter, exp-partials at fixed base 10
        int g = tid & 7, r = tid >> 3;
        float esum = 0.f;
        for (int it = 0; it < 8; ++it) {
            int nl = it * 32 + r;
            if (nl < RQ) {
                int n = n0 + nl;
                float a = 0.f;
                if (BF16) {
                    const uint4* xr = (const uint4*)(Xb + ((size_t)b * NN + n) * DD);
                    uint4 c0 = xr[g], c1 = xr[g + 8];
                    unsigned int wsv[8] = {c0.x, c0.y, c0.z, c0.w, c1.x, c1.y, c1.z, c1.w};
                    #pragma unroll
                    for (int i = 0; i < 8; ++i) {
                        int col = (i < 4) ? (8 * g + 2 * i) : (64 + 8 * g + 2 * (i - 4));
                        a += bf2f(wsv[i] & 0xffffu) * gqv[col] + bf2f(wsv[i] >> 16) * gqv[col + 1];
                    }
                } else {
                    const float4* xr = (const float4*)(X + xoff + (size_t)n * DD);
                    #pragma unroll
                    for (int i = 0; i < 4; ++i) {
                        float4 v = xr[g + 8 * i];
                        int col = 4 * (g + 8 * i);
                        a += v.x * gqv[col] + v.y * gqv[col + 1]
                           + v.z * gqv[col + 2] + v.w * gqv[col + 3];
                    }
                }
                a += __shfl_xor(a, 1, 8);
                a += __shfl_xor(a, 2, 8);
                a += __shfl_xor(a, 4, 8);
                if (g == 0) {
                    float l = 10.0f * tanhf(a);
                    if (get_mask(mask, f, (size_t)b * NN + n)) l = NEG;
                    lgl[nl] = l;
                    esum += __expf(l - 10.0f);      // logits <= 10 always
                }
            }
        }
        #pragma unroll
        for (int off = 32; off >= 1; off >>= 1) esum += __shfl_xor(esum, off, 64);
        if ((tid & 63) == 0) redw[tid >> 6] = esum;
        __syncthreads();
        if (tid == 0) ssum[(size_t)b * QQ + q] = redw[0] + redw[1] + redw[2] + redw[3];
    }
    grid.sync();

    // ================= phase 4: lse + store ================================
    {
        float s = ssum[(size_t)b * QQ] + ssum[(size_t)b * QQ + 1]
                + ssum[(size_t)b * QQ + 2] + ssum[(size_t)b * QQ + 3];
        float lse = 10.0f + logf(s);
        for (int nl = tid; nl < RQ; nl += 256)
            out[(size_t)b * NN + n0 + nl] = lgl[nl] - lse;
    }
}

// ===========================================================================
// Fallback: proven round-3 mega-kernel (one block per b, 1024 threads).
// ===========================================================================
template<int BF16>
__global__ __launch_bounds__(1024) void k_fused(
        const float* __restrict__ X, const float* __restrict__ Wnode,
        const float* __restrict__ Wfix, const float* __restrict__ Wstep,
        const float* __restrict__ Wout, const int* __restrict__ prev,
        const int* __restrict__ first, const void* __restrict__ mask,
        unsigned short* __restrict__ Xb, float* __restrict__ out) {
    int b = blockIdx.x, tid = threadIdx.x;

    __shared__ __align__(16) float cm[HH * 1024];
    __shared__ __align__(16) float qkl[HH * DD];
    __shared__ __align__(16) float qpart[8 * DD];
    __shared__ float xa[HH * DD];
    __shared__ float ge[DD], q[DD], sc[2 * DD], hd[DD], gl[DD], gqv[DD];
    __shared__ float red[16], invh[8];
    __shared__ int s_flag;

    const size_t xoff = (size_t)b * NN * DD;

    if (tid < 64) {
        const unsigned int* mw = (const unsigned int*)mask;
        unsigned int a0 = mw[tid], a1 = mw[tid + 64], a2 = mw[tid + 128], a3 = mw[tid + 192];
        int ii = (a0 <= 1u) && (a1 <= 1u) && (a2 <= 1u) && (a3 <= 1u);
        int ff = (a0 == 0u || a0 == 0x3F800000u) && (a1 == 0u || a1 == 0x3F800000u) &&
                 (a2 == 0u || a2 == 0x3F800000u) && (a3 == 0u || a3 == 0x3F800000u);
        int ai = __all(ii), af = __all(ff);
        if (tid == 0) s_flag = ai ? 1 : (af ? 2 : 0);
    }
    if (tid >= 256 && tid < 512) {
        int t = tid - 256;
        int src = (t < DD) ? first[b] : prev[b];
        sc[t] = X[xoff + (size_t)src * DD + (t & 127)];
    }

    {
        float4* red4 = (float4*)cm;
        int c = tid & 31, s = tid >> 5;
        const float4* Xr = (const float4*)(X + xoff);
        float4 acc = make_float4(0.f, 0.f, 0.f, 0.f);
        for (int n = s; n < NN; n += 32) {
            float4 v = Xr[n * 32 + c];
            acc.x += v.x; acc.y += v.y; acc.z += v.z; acc.w += v.w;
            if (BF16) {
                uint2 p;
                p.x = (unsigned)f2bf(v.x) | ((unsigned)f2bf(v.y) << 16);
                p.y = (unsigned)f2bf(v.z) | ((unsigned)f2bf(v.w) << 16);
                ((uint2*)Xb)[(size_t)b * NN * 32 + n * 32 + c] = p;
            }
        }
        red4[s * 32 + c] = acc;
        __syncthreads();
        for (int st = 16; st >= 1; st >>= 1) {
            if (s < st) {
                float4 o = red4[(s + st) * 32 + c];
                float4 r = red4[s * 32 + c];
                r.x += o.x; r.y += o.y; r.z += o.z; r.w += o.w;
                red4[s * 32 + c] = r;
            }
            __syncthreads();
        }
        if (s == 0) {
            float4 r = red4[c];
            ge[4 * c]     = r.x * (1.0f / NN);
            ge[4 * c + 1] = r.y * (1.0f / NN);
            ge[4 * c + 2] = r.z * (1.0f / NN);
            ge[4 * c + 3] = r.w * (1.0f / NN);
        }
        __syncthreads();
    }
    const int flag = s_flag;

    {
        int p = tid >> 7, d = tid & 127;
        float a = 0.f;
        #pragma unroll 4
        for (int k = p * 16; k < p * 16 + 16; ++k) a += ge[k] * Wfix[k * DD + d];
        #pragma unroll 4
        for (int k = p * 32; k < p * 32 + 32; ++k) a += sc[k] * Wstep[k * DD + d];
        qpart[p * DD + d] = a;
        __syncthreads();
        if (tid < DD) {
            float s = 0.f;
            #pragma unroll
            for (int pp = 0; pp < 8; ++pp) s += qpart[pp * DD + tid];
            q[tid] = s;
        }
        __syncthreads();
        int d2 = tid >> 3, h = tid & 7;
        const float4* wr = (const float4*)(Wnode + (size_t)d2 * 384 + h * 16);
        float a2 = 0.f;
        #pragma unroll
        for (int j4 = 0; j4 < 4; ++j4) {
            float4 w = wr[j4];
            a2 += w.x * q[h * 16 + 4 * j4]     + w.y * q[h * 16 + 4 * j4 + 1]
                + w.z * q[h * 16 + 4 * j4 + 2] + w.w * q[h * 16 + 4 * j4 + 3];
        }
        qkl[h * DD + d2] = 0.25f * a2;
        __syncthreads();
    }

    {
        int g = tid & 7;
        for (int it = 0; it < 8; ++it) {
            int n = it * 128 + (tid >> 3);
            if (n < NN) {
                float acc[HH] = {0.f, 0.f, 0.f, 0.f, 0.f, 0.f, 0.f, 0.f};
                if (BF16) {
                    const uint4* xr = (const uint4*)(Xb + xoff + (size_t)n * DD);
                    uint4 c0 = xr[g], c1 = xr[g + 8];
                    unsigned int wsv[8] = {c0.x, c0.y, c0.z, c0.w, c1.x, c1.y, c1.z, c1.w};
                    #pragma unroll
                    for (int i = 0; i < 8; ++i) {
                        int col = (i < 4) ? (8 * g + 2 * i) : (64 + 8 * g + 2 * (i - 4));
                        float lo = bf2f(wsv[i] & 0xffffu), hi = bf2f(wsv[i] >> 16);
                        #pragma unroll
                        for (int h = 0; h < HH; ++h)
                            acc[h] += lo * qkl[h * DD + col] + hi * qkl[h * DD + col + 1];
                    }
                } else {
                    const float4* xr = (const float4*)(X + xoff + (size_t)n * DD);
                    #pragma unroll
                    for (int i = 0; i < 4; ++i) {
                        float4 v = xr[g + 8 * i];
                        int col = 4 * (g + 8 * i);
                        #pragma unroll
                        for (int h = 0; h < HH; ++h)
                            acc[h] += v.x * qkl[h * DD + col]     + v.y * qkl[h * DD + col + 1]
                                    + v.z * qkl[h * DD + col + 2] + v.w * qkl[h * DD + col + 3];
                    }
                }
                #pragma unroll
                for (int h = 0; h < HH; ++h) {
                    acc[h] += __shfl_xor(acc[h], 1, 8);
                    acc[h] += __shfl_xor(acc[h], 2, 8);
                    acc[h] += __shfl_xor(acc[h], 4, 8);
                }
                float val = acc[0];
                #pragma unroll
                for (int h = 1; h < HH; ++h) val = (g == h) ? acc[h] : val;
                bool mk = get_mask(mask, flag, (size_t)b * NN + n);
                cm[g * 1024 + n] = mk ? NEG : val;
            }
        }
        __syncthreads();
    }

    {
        int h = tid >> 7, lane = tid & 127;
        float mx = -INFINITY;
        for (int n = lane; n < NN; n += 128) mx = fmaxf(mx, cm[h * 1024 + n]);
        #pragma unroll
        for (int off = 32; off >= 1; off >>= 1) mx = fmaxf(mx, __shfl_xor(mx, off, 64));
        if ((tid & 63) == 0) red[tid >> 6] = mx;
        __syncthreads();
        float m_h = fmaxf(red[2 * h], red[2 * h + 1]);
        float sm = 0.f;
        for (int n = lane; n < NN; n += 128) {
            float p = __expf(cm[h * 1024 + n] - m_h);
            cm[h * 1024 + n] = p;
            sm += p;
        }
        #pragma unroll
        for (int off = 32; off >= 1; off >>= 1) sm += __shfl_xor(sm, off, 64);
        __syncthreads();
        if ((tid & 63) == 0) red[tid >> 6] = sm;
        __syncthreads();
        if (tid < HH) invh[tid] = 1.0f / (red[2 * tid] + red[2 * tid + 1]);
        __syncthreads();
    }

    {
        int s = tid >> 7, d = tid & 127;
        float acc[HH] = {0.f, 0.f, 0.f, 0.f, 0.f, 0.f, 0.f, 0.f};
        for (int n = s; n < NN; n += 8) {
            float x = BF16 ? bf2f((unsigned int)Xb[xoff + (size_t)n * DD + d])
                           : X[xoff + (size_t)n * DD + d];
            #pragma unroll
            for (int h = 0; h < HH; ++h) acc[h] += cm[h * 1024 + n] * x;
        }
        __syncthreads();
        float* xp = cm;
        #pragma unroll
        for (int h = 0; h < HH; ++h) xp[(s * HH + h) * DD + d] = acc[h];
        __syncthreads();
        if (s == 0) {
            #pragma unroll
            for (int h = 0; h < HH; ++h) {
                float t = 0.f;
                #pragma unroll
                for (int ss = 0; ss < 8; ++ss) t += xp[(ss * HH + h) * DD + d];
                xa[h * DD + d] = t * invh[h];
            }
        }
        __syncthreads();
    }

    {
        int p = tid >> 7, t = tid & 127;
        int h = t >> 4;
        float a = 0.f;
        #pragma unroll 4
        for (int d = p * 16; d < p * 16 + 16; ++d)
            a += xa[h * DD + d] * Wnode[(size_t)d * 384 + 128 + t];
        qpart[p * DD + t] = a;
        __syncthreads();
        if (tid < DD) {
            float s = 0.f;
            #pragma unroll
            for (int pp = 0; pp < 8; ++pp) s += qpart[pp * DD + tid];
            hd[tid] = s;
        }
        __syncthreads();
        a = 0.f;
        #pragma unroll 4
        for (int k = p * 16; k < p * 16 + 16; ++k) a += hd[k] * Wout[(size_t)k * DD + t];
        qpart[p * DD + t] = a;
        __syncthreads();
        if (tid < DD) {
            float s = 0.f;
            #pragma unroll
            for (int pp = 0; pp < 8; ++pp) s += qpart[pp * DD + tid];
            gl[tid] = s;
        }
        __syncthreads();
        const float4* wr = (const float4*)(Wnode + (size_t)t * 384 + 256 + p * 16);
        a = 0.f;
        #pragma unroll
        for (int j4 = 0; j4 < 4; ++j4) {
            float4 w = wr[j4];
            int k = p * 16 + 4 * j4;
            a += w.x * gl[k] + w.y * gl[k + 1] + w.z * gl[k + 2] + w.w * gl[k + 3];
        }
        qpart[p * DD + t] = a;
        __syncthreads();
        if (tid < DD) {
            float s = 0.f;
            #pragma unroll
            for (int pp = 0; pp < 8; ++pp) s += qpart[pp * DD + tid];
            gqv[tid] = s * 0.08838834764831845f;
        }
        __syncthreads();
    }

    {
        float* lg = qkl;
        int g = tid & 7;
        for (int it = 0; it < 8; ++it) {
            int n = it * 128 + (tid >> 3);
            if (n < NN) {
                float a = 0.f;
                if (BF16) {
                    const uint4* xr = (const uint4*)(Xb + xoff + (size_t)n * DD);
                    uint4 c0 = xr[g], c1 = xr[g + 8];
                    unsigned int wsv[8] = {c0.x, c0.y, c0.z, c0.w, c1.x, c1.y, c1.z, c1.w};
                    #pragma unroll
                    for (int i = 0; i < 8; ++i) {
                        int col = (i < 4) ? (8 * g + 2 * i) : (64 + 8 * g + 2 * (i - 4));
                        a += bf2f(wsv[i] & 0xffffu) * gqv[col] + bf2f(wsv[i] >> 16) * gqv[col + 1];
                    }
                } else {
                    const float4* xr = (const float4*)(X + xoff + (size_t)n * DD);
                    #pragma unroll
                    for (int i = 0; i < 4; ++i) {
                        float4 v = xr[g + 8 * i];
                        int col = 4 * (g + 8 * i);
                        a += v.x * gqv[col] + v.y * gqv[col + 1] + v.z * gqv[col + 2] + v.w * gqv[col + 3];
                    }
                }
                a += __shfl_xor(a, 1, 8);
                a += __shfl_xor(a, 2, 8);
                a += __shfl_xor(a, 4, 8);
                if (g == 0) {
                    float lgt = 10.0f * tanhf(a);
                    lg[n] = get_mask(mask, flag, (size_t)b * NN + n) ? NEG : lgt;
                }
            }
        }
        __syncthreads();
        float v = (tid < NN) ? lg[tid] : -INFINITY;
        float mx = v;
        #pragma unroll
        for (int off = 32; off >= 1; off >>= 1) mx = fmaxf(mx, __shfl_xor(mx, off, 64));
        if ((tid & 63) == 0) red[tid >> 6] = mx;
        __syncthreads();
        float m = red[0];
        #pragma unroll
        for (int w = 1; w < 16; ++w) m = fmaxf(m, red[w]);
        float e = (tid < NN) ? __expf(v - m) : 0.f;
        float sm = e;
        #pragma unroll
        for (int off = 32; off >= 1; off >>= 1) sm += __shfl_xor(sm, off, 64);
        __syncthreads();
        if ((tid & 63) == 0) red[tid >> 6] = sm;
        __syncthreads();
        float s2 = 0.f;
        #pragma unroll
        for (int w = 0; w < 16; ++w) s2 += red[w];
        float lse = m + logf(s2);
        if (tid < NN) out[(size_t)b * NN + tid] = v - lse;
    }
}

// ---------------------------------------------------------------------------
extern "C" void kernel_launch(void* const* d_in, const int* in_sizes, int n_in,
                              void* d_out, int out_size, void* d_ws, size_t ws_size,
                              hipStream_t stream) {
    const float* X     = (const float*)d_in[0];
    const float* Wnode = (const float*)d_in[1];
    const float* Wfix  = (const float*)d_in[2];
    const float* Wstep = (const float*)d_in[3];
    const float* Wout  = (const float*)d_in[4];
    const int*   prev  = (const int*)d_in[5];
    const int*   first = (const int*)d_in[6];
    const void*  mask  = d_in[7];
    float* out = (float*)d_out;

    char* wsb = (char*)d_ws;
    int*   flag    = (int*)wsb;
    float* partial = (float*)(wsb + 256);
    float* mqw     = partial + (size_t)BB * QQ * DD;
    float* sqw     = mqw + (size_t)BB * QQ * HH;
    float* pvp     = sqw + (size_t)BB * QQ * HH;
    float* ssum    = pvp + (size_t)BB * QQ * HH * DD;
    const size_t scratch_end = 256 + sizeof(float) *
        ((size_t)BB * QQ * DD + 2 * (size_t)BB * QQ * HH +
         (size_t)BB * QQ * HH * DD + (size_t)BB * QQ);
    const size_t xb_off = (scratch_end + 255) & ~(size_t)255;
    unsigned short* Xb = (unsigned short*)(wsb + xb_off);
    const size_t coop_need_bf16 = xb_off + (size_t)2 * BB * NN * DD;

    bool launched = false;
    if (ws_size >= scratch_end) {
        const int want_bf16 = (ws_size >= coop_need_bf16) ? 1 : 0;
        const void* kptr = want_bf16 ? (const void*)k_coop<1> : (const void*)k_coop<0>;
        int maxb = 0;
        if (hipOccupancyMaxActiveBlocksPerMultiprocessor(&maxb, kptr, 256, 0) == hipSuccess
            && maxb >= 4) {
            unsigned short* xbp = want_bf16 ? Xb : nullptr;
            void* args[] = {(void*)&X, (void*)&Wnode, (void*)&Wfix, (void*)&Wstep,
                            (void*)&Wout, (void*)&prev, (void*)&first, (void*)&mask,
                            (void*)&flag, (void*)&partial, (void*)&mqw, (void*)&sqw,
                            (void*)&pvp, (void*)&ssum, (void*)&xbp, (void*)&out};
            dim3 g(BB * QQ), blk(256);
            launched = (hipLaunchCooperativeKernel(kptr, g, blk, args, 0, stream)
                        == hipSuccess);
        }
    }
    if (!launched) {
        // proven round-3 mega-kernel fallback
        const size_t mega_need = 256 + (size_t)2 * BB * NN * DD;
        if (ws_size >= mega_need) {
            unsigned short* Xm = (unsigned short*)(wsb + 256);
            k_fused<1><<<BB, 1024, 0, stream>>>(X, Wnode, Wfix, Wstep, Wout,
                                                prev, first, mask, Xm, out);
        } else {
            k_fused<0><<<BB, 1024, 0, stream>>>(X, Wnode, Wfix, Wstep, Wout,
                                                prev, first, mask, nullptr, out);
        }
    }
}